// Round 8
// baseline (340.539 us; speedup 1.0000x reference)
//
#include <hip/hip_runtime.h>
#include <hip/hip_bf16.h>

typedef __attribute__((ext_vector_type(8)))  short short8;
typedef __attribute__((ext_vector_type(4)))  float floatx4;
typedef __attribute__((ext_vector_type(16))) float floatx16;

#define BB 32
#define CC 256
#define OO 256
#define KS 7
#define HH 31
#define WW 31
#define HO 25
#define PP 625
#define SS 49

#define SLAB_PITCH 40        // ushort elems per pos row: 32 ci + 8 pad = 80 B
#define SLAB_ROWS  372       // p-tile 128 spans <= 12 x-rows; 12*31 = 372

// wt4 / wmod layout: [s][cb][kh][o][16ci]  (elems per (s,cb) = 2*256*16 = 8192)
#define WT4_ELEMS  ((size_t)SS * 8 * 2 * CC * 16)        // 3,211,264
#define WT4_BYTES  (WT4_ELEMS * 2)                       // 6,422,528
#define KERNF_BYTES ((size_t)BB * SS * CC * 4)           // 1,605,632
#define WMOD_ELEMS ((size_t)BB * WT4_ELEMS)
#define WMOD_BYTES (WMOD_ELEMS * 2)                      // 205,520,896

static __device__ __forceinline__ unsigned pk2(float lo, float hi) {
    float2 f; f.x = lo; f.y = hi;
    __hip_bfloat162 h = __float22bfloat162_rn(f);   // v_cvt_pk_bf16_f32
    unsigned r;
    __builtin_memcpy(&r, &h, sizeof(r));
    return r;
}
static __device__ __forceinline__ float bflo(unsigned u) {
    return __builtin_bit_cast(float, u << 16);
}
static __device__ __forceinline__ float bfhi(unsigned u) {
    return __builtin_bit_cast(float, u & 0xffff0000u);
}

// modulated pack: 8 bf16 = bf16( wt[j] * k[j] )
static __device__ __forceinline__ uint4 modpack(uint4 wv, float4 k0, float4 k1) {
    float p0 = bflo(wv.x) * k0.x, p1 = bfhi(wv.x) * k0.y;
    float p2 = bflo(wv.y) * k0.z, p3 = bfhi(wv.y) * k0.w;
    float p4 = bflo(wv.z) * k1.x, p5 = bfhi(wv.z) * k1.y;
    float p6 = bflo(wv.w) * k1.z, p7 = bfhi(wv.w) * k1.w;
    uint4 r;
    r.x = pk2(p0, p1); r.y = pk2(p2, p3); r.z = pk2(p4, p5); r.w = pk2(p6, p7);
    return r;
}

// ---------------------------------------------------------------------------
// Prepass A: w[o][c][s] f32 -> wt4[s][cb][kh][o][16] bf16. Grid 392 = (s*8+cb).
// ---------------------------------------------------------------------------
__global__ __launch_bounds__(256) void repack_w(const float* __restrict__ w,
                                                unsigned short* __restrict__ wt4) {
    const int bid = blockIdx.x;           // = s*8 + cb
    const int s = bid >> 3, cb = bid & 7;
    const int o = threadIdx.x;
    const float* src = w + ((size_t)o * CC + cb * 32) * SS + s;
    float v[32];
#pragma unroll
    for (int ci = 0; ci < 32; ++ci) v[ci] = src[(size_t)ci * SS];
#pragma unroll
    for (int kh = 0; kh < 2; ++kh) {
        unsigned short* dst = wt4 + ((size_t)bid * 2 + kh) * (CC * 16) + o * 16;
        uint4 p0, p1;
        p0.x = pk2(v[kh*16+0], v[kh*16+1]);  p0.y = pk2(v[kh*16+2], v[kh*16+3]);
        p0.z = pk2(v[kh*16+4], v[kh*16+5]);  p0.w = pk2(v[kh*16+6], v[kh*16+7]);
        p1.x = pk2(v[kh*16+8], v[kh*16+9]);  p1.y = pk2(v[kh*16+10], v[kh*16+11]);
        p1.z = pk2(v[kh*16+12], v[kh*16+13]); p1.w = pk2(v[kh*16+14], v[kh*16+15]);
        *(uint4*)(dst)     = p0;
        *(uint4*)(dst + 8) = p1;
    }
}

// ---------------------------------------------------------------------------
// Prepass B (fallback path only): kern[b][c][s] -> kernf[b][s][c] f32.
// ---------------------------------------------------------------------------
__global__ __launch_bounds__(256) void repack_k(const float* __restrict__ kern,
                                                float* __restrict__ kernf) {
    const int bid = blockIdx.x;
    const int b = bid / KS, kk = bid % KS;
    const int c = threadIdx.x;
    const float* src = kern + ((size_t)b * CC + c) * SS + kk * KS;
#pragma unroll
    for (int ll = 0; ll < KS; ++ll)
        kernf[((size_t)b * SS + kk * KS + ll) * CC + c] = src[ll];
}

// ---------------------------------------------------------------------------
// Premod: wmod[b][s][cb][kh][o][16] = wt4 * kern[b][c][s]. Grid 12544 = b*392+.
// kern reads are block-uniform (scalar loads); streaming writes 205 MB.
// ---------------------------------------------------------------------------
__global__ __launch_bounds__(256) void premod(
        const unsigned short* __restrict__ wt4, const float* __restrict__ kern,
        unsigned short* __restrict__ wmod) {
    const int bid = blockIdx.x;
    const int b = bid / 392, rc = bid % 392;
    const int s = rc >> 3, cb = rc & 7;
    const int o = threadIdx.x;
    const float* kp = kern + ((size_t)b * CC + cb * 32) * SS + s;
    float kf[32];
#pragma unroll
    for (int ci = 0; ci < 32; ++ci) kf[ci] = kp[(size_t)ci * SS];
#pragma unroll
    for (int kh = 0; kh < 2; ++kh) {
        const size_t off = ((size_t)rc * 2 + kh) * (CC * 16) + o * 16;
        uint4 w0 = *(const uint4*)(wt4 + off);
        uint4 w1 = *(const uint4*)(wt4 + off + 8);
        float4 k0a, k0b, k1a, k1b;
        k0a.x = kf[kh*16+0];  k0a.y = kf[kh*16+1];  k0a.z = kf[kh*16+2];  k0a.w = kf[kh*16+3];
        k0b.x = kf[kh*16+4];  k0b.y = kf[kh*16+5];  k0b.z = kf[kh*16+6];  k0b.w = kf[kh*16+7];
        k1a.x = kf[kh*16+8];  k1a.y = kf[kh*16+9];  k1a.z = kf[kh*16+10]; k1a.w = kf[kh*16+11];
        k1b.x = kf[kh*16+12]; k1b.y = kf[kh*16+13]; k1b.z = kf[kh*16+14]; k1b.w = kf[kh*16+15];
        uint4 m0 = modpack(w0, k0a, k0b);
        uint4 m1 = modpack(w1, k1a, k1b);
        unsigned short* dst = wmod + (size_t)b * WT4_ELEMS + off;
        *(uint4*)(dst)     = m0;
        *(uint4*)(dst + 8) = m1;
    }
}

// ---------------------------------------------------------------------------
// Main: block = 64o x 128p of one batch, 4 waves k-split (s quarters), each
// wave computes the full 64o x 128p tile over its s-range. Per s-step:
// 4 global b128 A (premodulated, L2-hot), 8 ds b128 B, 16x mfma_32x32x16
// (129 cyc MFMA per step -> depth-1 prefetch covers L2 latency; A bytes per
// FLOP halved vs the 64p tile). Grid 640, XCD-pinned (5 px blocks of one
// (b,oy) share a 1.6 MB wmod slice in their XCD's L2).
// ---------------------------------------------------------------------------
__global__ __launch_bounds__(256, 2) void dwconv_big(
        const float* __restrict__ x, const unsigned short* __restrict__ wmod,
        const float* __restrict__ bias, float* __restrict__ out) {
    __shared__ unsigned short slab[SLAB_ROWS * SLAB_PITCH];   // 29760 B

    const int tid = threadIdx.x;
    const int id = blockIdx.x;
    // id = hi*40 + px*8 + j ; group g = hi*8 + j = b*4+oy. The 5 px blocks of
    // a group share id%8 -> same XCD under round-robin dispatch.
    const int hi = id / 40, rem = id % 40;
    const int px = rem >> 3;
    const int g = hi * 8 + (rem & 7);
    const int b = g >> 2, oy = g & 3;

    const int p0 = px * 128, o0 = oy * 64;
    const int h0 = p0 / HO;
    const int pmax = (p0 + 127 < PP - 1) ? p0 + 127 : PP - 1;
    const int rows = pmax / HO - h0 + 7;          // <= 12
    const int npos = rows * WW;

    const int lane = tid & 63, kw = tid >> 6;
    const int l32 = lane & 31, half = lane >> 5;  // half: k-oct within frag

    // B-fragment LDS offsets (ushort elems) for 4 p-subtiles of 32
    int bOff[4];
#pragma unroll
    for (int ph = 0; ph < 4; ++ph) {
        int p = p0 + ph * 32 + l32;
        if (p > PP - 1) p = PP - 1;               // clamp; store guarded later
        int h = p / HO, ww_ = p - h * HO;
        bOff[ph] = ((h - h0) * WW + ww_) * SLAB_PITCH + half * 8;
    }

    const int s0 = kw * 12 + (kw > 0 ? 1 : 0);    // 0,13,25,37
    const int ns = kw ? 12 : 13;

    const unsigned short* wmodb = wmod + (size_t)b * WT4_ELEMS
                                  + (size_t)(o0 + l32) * 16 + half * 8;

    floatx16 acc[2][4];
#pragma unroll
    for (int oh = 0; oh < 2; ++oh)
#pragma unroll
        for (int ph = 0; ph < 4; ++ph)
#pragma unroll
            for (int r = 0; r < 16; ++r) acc[oh][ph][r] = 0.f;

    for (int cb = 0; cb < 8; ++cb) {
        __syncthreads();   // prior compute done: slab safe to overwrite
        // ---- stage x slab: slabT[pos][ci] bf16, 4 waves x 8 channels ----
        {
            const float* xsrc = x + ((size_t)(b * CC + cb * 32 + kw * 8)) * (HH * WW)
                                  + h0 * WW;
#pragma unroll
            for (int it = 0; it < 6; ++it) {
                int pos = lane + it * 64;
                if (pos < npos) {
                    float v[8];
#pragma unroll
                    for (int j = 0; j < 8; ++j) v[j] = xsrc[j * (HH * WW) + pos];
                    uint4 pkt;
                    pkt.x = pk2(v[0], v[1]); pkt.y = pk2(v[2], v[3]);
                    pkt.z = pk2(v[4], v[5]); pkt.w = pk2(v[6], v[7]);
                    *(uint4*)(slab + pos * SLAB_PITCH + kw * 8) = pkt;
                }
            }
        }
        __syncthreads();

        // rolling A pointer: frag(oh,kh) = aptr + oh*512 + kh*4096; +65536/s
        const unsigned short* aptr = wmodb + (size_t)(s0 * 8 + cb) * 8192;

        uint4 wa0 = *(const uint4*)(aptr);
        uint4 wa1 = *(const uint4*)(aptr + 512);
        uint4 wa2 = *(const uint4*)(aptr + 4096);
        uint4 wa3 = *(const uint4*)(aptr + 4096 + 512);

        int kk = s0 / KS, ll = s0 - (s0 / KS) * KS;
        for (int si = 0; si < ns; ++si) {
            // prefetch s+1
            uint4 wn0, wn1, wn2, wn3;
            if (si + 1 < ns) {
                aptr += 65536;
                wn0 = *(const uint4*)(aptr);
                wn1 = *(const uint4*)(aptr + 512);
                wn2 = *(const uint4*)(aptr + 4096);
                wn3 = *(const uint4*)(aptr + 4096 + 512);
            } else {
                wn0 = wa0; wn1 = wa1; wn2 = wa2; wn3 = wa3;
            }

            const unsigned short* slabS = slab + (kk * WW + ll) * SLAB_PITCH;
            short8 a00 = __builtin_bit_cast(short8, wa0);  // oh0 kh0
            short8 a10 = __builtin_bit_cast(short8, wa1);  // oh1 kh0
            short8 a01 = __builtin_bit_cast(short8, wa2);  // oh0 kh1
            short8 a11 = __builtin_bit_cast(short8, wa3);  // oh1 kh1

#pragma unroll
            for (int ph = 0; ph < 4; ++ph) {
                short8 sbk0 = *(const short8*)(slabS + bOff[ph]);
                short8 sbk1 = *(const short8*)(slabS + bOff[ph] + 16);
                acc[0][ph] = __builtin_amdgcn_mfma_f32_32x32x16_bf16(a00, sbk0, acc[0][ph], 0, 0, 0);
                acc[1][ph] = __builtin_amdgcn_mfma_f32_32x32x16_bf16(a10, sbk0, acc[1][ph], 0, 0, 0);
                acc[0][ph] = __builtin_amdgcn_mfma_f32_32x32x16_bf16(a01, sbk1, acc[0][ph], 0, 0, 0);
                acc[1][ph] = __builtin_amdgcn_mfma_f32_32x32x16_bf16(a11, sbk1, acc[1][ph], 0, 0, 0);
            }

            wa0 = wn0; wa1 = wn1; wa2 = wn2; wa3 = wn3;
            if (++ll == KS) { ll = 0; ++kk; }
        }
    }

    // ---- epilogue: 4-way kw reduction via LDS, 2 rounds of 64 p ----------
    // D layout (32x32): col p = l32, row o = (reg&3) + 8*(reg>>2) + 4*half.
    float* red = (float*)slab;   // [64][68] f32 = 17408 B <= 29760
#pragma unroll
    for (int round = 0; round < 2; ++round) {
        __syncthreads();
        if (kw == 3) {
#pragma unroll
            for (int oh = 0; oh < 2; ++oh)
#pragma unroll
                for (int phl = 0; phl < 2; ++phl)
#pragma unroll
                    for (int c = 0; c < 4; ++c) {
                        const int ph = round * 2 + phl;
                        floatx4 v4 = {acc[oh][ph][4*c+0], acc[oh][ph][4*c+1],
                                      acc[oh][ph][4*c+2], acc[oh][ph][4*c+3]};
                        *(floatx4*)(red + (phl * 32 + l32) * 68 + oh * 32 + c * 8 + 4 * half) = v4;
                    }
        }
        __syncthreads();
        if (kw == 2) {
#pragma unroll
            for (int oh = 0; oh < 2; ++oh)
#pragma unroll
                for (int phl = 0; phl < 2; ++phl)
#pragma unroll
                    for (int c = 0; c < 4; ++c) {
                        const int ph = round * 2 + phl;
                        float* rp = red + (phl * 32 + l32) * 68 + oh * 32 + c * 8 + 4 * half;
                        floatx4 v4 = *(floatx4*)rp;
                        v4[0] += acc[oh][ph][4*c+0]; v4[1] += acc[oh][ph][4*c+1];
                        v4[2] += acc[oh][ph][4*c+2]; v4[3] += acc[oh][ph][4*c+3];
                        *(floatx4*)rp = v4;
                    }
        }
        __syncthreads();
        if (kw == 1) {
#pragma unroll
            for (int oh = 0; oh < 2; ++oh)
#pragma unroll
                for (int phl = 0; phl < 2; ++phl)
#pragma unroll
                    for (int c = 0; c < 4; ++c) {
                        const int ph = round * 2 + phl;
                        float* rp = red + (phl * 32 + l32) * 68 + oh * 32 + c * 8 + 4 * half;
                        floatx4 v4 = *(floatx4*)rp;
                        v4[0] += acc[oh][ph][4*c+0]; v4[1] += acc[oh][ph][4*c+1];
                        v4[2] += acc[oh][ph][4*c+2]; v4[3] += acc[oh][ph][4*c+3];
                        *(floatx4*)rp = v4;
                    }
        }
        __syncthreads();
        if (kw == 0) {
#pragma unroll
            for (int oh = 0; oh < 2; ++oh)
#pragma unroll
                for (int c = 0; c < 4; ++c) {
                    const int ob = o0 + oh * 32 + c * 8 + 4 * half;
                    const float4 bv = *(const float4*)(bias + ob);
#pragma unroll
                    for (int phl = 0; phl < 2; ++phl) {
                        const int ph = round * 2 + phl;
                        const int p = p0 + ph * 32 + l32;
                        floatx4 v4 = *(floatx4*)(red + (phl * 32 + l32) * 68 + oh * 32 + c * 8 + 4 * half);
                        if (p < PP) {
                            out[((size_t)(b * OO + ob + 0)) * PP + p] = v4[0] + acc[oh][ph][4*c+0] + bv.x;
                            out[((size_t)(b * OO + ob + 1)) * PP + p] = v4[1] + acc[oh][ph][4*c+1] + bv.y;
                            out[((size_t)(b * OO + ob + 2)) * PP + p] = v4[2] + acc[oh][ph][4*c+2] + bv.z;
                            out[((size_t)(b * OO + ob + 3)) * PP + p] = v4[3] + acc[oh][ph][4*c+3] + bv.w;
                        }
                    }
                }
        }
    }
}

// ---------------------------------------------------------------------------
// Fallback path (ws >= 8 MB): R5 kernel adapted to wt4 layout. ~270 us.
// ---------------------------------------------------------------------------
__global__ __launch_bounds__(256, 3) void dwconv_mid(
        const float* __restrict__ x,
        const unsigned short* __restrict__ wt4, const float* __restrict__ kernf,
        const float* __restrict__ bias, float* __restrict__ out) {
    __shared__ unsigned short slab[SLAB_ROWS * SLAB_PITCH];   // 29760 B

    const int tid = threadIdx.x;
    const int id = blockIdx.x;
    const int oy = id & 3;
    const int t  = id >> 2;
    const int px = t % 5, b = t / 5;
    const int p0 = px * 128, o0 = oy * 64;
    const int h0 = p0 / HO;
    const int rows = (HH - h0) < 12 ? (HH - h0) : 12;
    const int npos = rows * WW;

    const int lane = tid & 63, wid = tid >> 6;
    const int pw = wid & 1, kw = wid >> 1;
    const int lo16 = lane & 15, quad = lane >> 4;

    int bOff[4];
#pragma unroll
    for (int pt = 0; pt < 4; ++pt) {
        int p = p0 + pw * 64 + pt * 16 + lo16;
        if (p > PP - 1) p = PP - 1;
        int h = p / HO, ww_ = p - h * HO;
        bOff[pt] = ((h - h0) * WW + ww_) * SLAB_PITCH + quad * 8;
    }

    const int s0 = kw ? 25 : 0;
    const int ns = kw ? 24 : 25;

    floatx4 acc[4][4];
#pragma unroll
    for (int at = 0; at < 4; ++at)
#pragma unroll
        for (int pt = 0; pt < 4; ++pt)
            acc[at][pt] = (floatx4){0.f, 0.f, 0.f, 0.f};

    for (int cb = 0; cb < 8; ++cb) {
        __syncthreads();
        {
            const int coct = wid;
            const float* xsrc = x + ((size_t)(b * CC + cb * 32 + coct * 8)) * (HH * WW)
                                  + h0 * WW;
#pragma unroll
            for (int it = 0; it < 6; ++it) {
                int pos = lane + it * 64;
                if (pos < npos) {
                    float v[8];
#pragma unroll
                    for (int j = 0; j < 8; ++j) v[j] = xsrc[j * (HH * WW) + pos];
                    uint4 pkt;
                    pkt.x = pk2(v[0], v[1]); pkt.y = pk2(v[2], v[3]);
                    pkt.z = pk2(v[4], v[5]); pkt.w = pk2(v[6], v[7]);
                    *(uint4*)(slab + pos * SLAB_PITCH + coct * 8) = pkt;
                }
            }
        }
        __syncthreads();

        const unsigned short* aptrA = wt4 +
            ((size_t)(s0 * 8 + cb) * 2 + (quad >> 1)) * 4096 +
            (size_t)(o0 + lo16) * 16 + (quad & 1) * 8;
        const float* kptr = kernf + ((size_t)b * SS + s0) * CC + cb * 32 + quad * 8;

        uint4 wa[4];
        wa[0] = *(const uint4*)(aptrA);
        wa[1] = *(const uint4*)(aptrA + 256);
        wa[2] = *(const uint4*)(aptrA + 512);
        wa[3] = *(const uint4*)(aptrA + 768);
        float4 kq0 = *(const float4*)(kptr);
        float4 kq1 = *(const float4*)(kptr + 4);

        for (int si = 0; si < ns; ++si) {
            const int s = s0 + si;
            uint4 wn[4]; float4 kn0, kn1;
            if (si + 1 < ns) {
                aptrA += 65536;
                kptr  += CC;
                wn[0] = *(const uint4*)(aptrA);
                wn[1] = *(const uint4*)(aptrA + 256);
                wn[2] = *(const uint4*)(aptrA + 512);
                wn[3] = *(const uint4*)(aptrA + 768);
                kn0 = *(const float4*)(kptr);
                kn1 = *(const float4*)(kptr + 4);
            } else {
                wn[0] = wa[0]; wn[1] = wa[1]; wn[2] = wa[2]; wn[3] = wa[3];
                kn0 = kq0; kn1 = kq1;
            }

            const int kk = s / KS, ll = s - kk * KS;
            const unsigned short* slabS = slab + (kk * WW + ll) * SLAB_PITCH;

            short8 sb0 = *(const short8*)(slabS + bOff[0]);
            short8 sb1 = *(const short8*)(slabS + bOff[1]);
            short8 sb2 = *(const short8*)(slabS + bOff[2]);
            short8 sb3 = *(const short8*)(slabS + bOff[3]);

            short8 sa0 = __builtin_bit_cast(short8, modpack(wa[0], kq0, kq1));
            short8 sa1 = __builtin_bit_cast(short8, modpack(wa[1], kq0, kq1));
            short8 sa2 = __builtin_bit_cast(short8, modpack(wa[2], kq0, kq1));
            short8 sa3 = __builtin_bit_cast(short8, modpack(wa[3], kq0, kq1));

            acc[0][0] = __builtin_amdgcn_mfma_f32_16x16x32_bf16(sa0, sb0, acc[0][0], 0, 0, 0);
            acc[0][1] = __builtin_amdgcn_mfma_f32_16x16x32_bf16(sa0, sb1, acc[0][1], 0, 0, 0);
            acc[0][2] = __builtin_amdgcn_mfma_f32_16x16x32_bf16(sa0, sb2, acc[0][2], 0, 0, 0);
            acc[0][3] = __builtin_amdgcn_mfma_f32_16x16x32_bf16(sa0, sb3, acc[0][3], 0, 0, 0);
            acc[1][0] = __builtin_amdgcn_mfma_f32_16x16x32_bf16(sa1, sb0, acc[1][0], 0, 0, 0);
            acc[1][1] = __builtin_amdgcn_mfma_f32_16x16x32_bf16(sa1, sb1, acc[1][1], 0, 0, 0);
            acc[1][2] = __builtin_amdgcn_mfma_f32_16x16x32_bf16(sa1, sb2, acc[1][2], 0, 0, 0);
            acc[1][3] = __builtin_amdgcn_mfma_f32_16x16x32_bf16(sa1, sb3, acc[1][3], 0, 0, 0);
            acc[2][0] = __builtin_amdgcn_mfma_f32_16x16x32_bf16(sa2, sb0, acc[2][0], 0, 0, 0);
            acc[2][1] = __builtin_amdgcn_mfma_f32_16x16x32_bf16(sa2, sb1, acc[2][1], 0, 0, 0);
            acc[2][2] = __builtin_amdgcn_mfma_f32_16x16x32_bf16(sa2, sb2, acc[2][2], 0, 0, 0);
            acc[2][3] = __builtin_amdgcn_mfma_f32_16x16x32_bf16(sa2, sb3, acc[2][3], 0, 0, 0);
            acc[3][0] = __builtin_amdgcn_mfma_f32_16x16x32_bf16(sa3, sb0, acc[3][0], 0, 0, 0);
            acc[3][1] = __builtin_amdgcn_mfma_f32_16x16x32_bf16(sa3, sb1, acc[3][1], 0, 0, 0);
            acc[3][2] = __builtin_amdgcn_mfma_f32_16x16x32_bf16(sa3, sb2, acc[3][2], 0, 0, 0);
            acc[3][3] = __builtin_amdgcn_mfma_f32_16x16x32_bf16(sa3, sb3, acc[3][3], 0, 0, 0);

            wa[0] = wn[0]; wa[1] = wn[1]; wa[2] = wn[2]; wa[3] = wn[3];
            kq0 = kn0; kq1 = kn1;
        }
    }

    float* red = (float*)slab;
    for (int round = 0; round < 2; ++round) {
        __syncthreads();
        if (kw == 1 && pw == round) {
#pragma unroll
            for (int at = 0; at < 4; ++at)
#pragma unroll
                for (int pt = 0; pt < 4; ++pt)
                    *(floatx4*)(red + (pt * 16 + lo16) * 68 + at * 16 + quad * 4)
                        = acc[at][pt];
        }
        __syncthreads();
        if (kw == 0 && pw == round) {
#pragma unroll
            for (int at = 0; at < 4; ++at) {
                const float4 bv = *(const float4*)(bias + o0 + at * 16 + quad * 4);
#pragma unroll
                for (int pt = 0; pt < 4; ++pt) {
                    floatx4 v = *(const floatx4*)(red + (pt * 16 + lo16) * 68
                                                  + at * 16 + quad * 4);
                    int p = p0 + round * 64 + pt * 16 + lo16;
                    if (p < PP) {
                        const int ob = o0 + at * 16 + quad * 4;
                        out[((size_t)(b * OO + ob + 0)) * PP + p] = acc[at][pt][0] + v[0] + bv.x;
                        out[((size_t)(b * OO + ob + 1)) * PP + p] = acc[at][pt][1] + v[1] + bv.y;
                        out[((size_t)(b * OO + ob + 2)) * PP + p] = acc[at][pt][2] + v[2] + bv.z;
                        out[((size_t)(b * OO + ob + 3)) * PP + p] = acc[at][pt][3] + v[3] + bv.w;
                    }
                }
            }
        }
    }
}

// ---------------------------------------------------------------------------
// Last-resort fallback: naive but correct.
// ---------------------------------------------------------------------------
__global__ __launch_bounds__(256) void dwconv_naive(
        const float* __restrict__ x, const float* __restrict__ kern,
        const float* __restrict__ w, const float* __restrict__ bias,
        float* __restrict__ out) {
    const int idx = blockIdx.x * 256 + threadIdx.x;
    if (idx >= BB * OO * PP) return;
    const int p = idx % PP;
    const int o = (idx / PP) % OO;
    const int b = idx / (PP * OO);
    const int h = p / HO;
    const int wq = p - h * HO;
    float acc = 0.f;
    for (int c = 0; c < CC; ++c) {
        const float* xp = x + ((size_t)(b * CC + c)) * (HH * WW) + h * WW + wq;
        const float* kp = kern + ((size_t)b * CC + c) * SS;
        const float* wp = w + ((size_t)o * CC + c) * SS;
#pragma unroll
        for (int s = 0; s < SS; ++s) {
            const int kk = s / KS;
            const int ll = s - kk * KS;
            acc += xp[kk * WW + ll] * kp[s] * wp[s];
        }
    }
    out[idx] = acc + bias[o];
}

extern "C" void kernel_launch(void* const* d_in, const int* in_sizes, int n_in,
                              void* d_out, int out_size, void* d_ws, size_t ws_size,
                              hipStream_t stream) {
    const float* x    = (const float*)d_in[0];
    const float* kern = (const float*)d_in[1];
    const float* w    = (const float*)d_in[2];
    const float* bias = (const float*)d_in[3];
    float* out = (float*)d_out;

    if (ws_size >= WT4_BYTES + WMOD_BYTES) {
        unsigned short* wt4  = (unsigned short*)d_ws;
        unsigned short* wmod = (unsigned short*)((char*)d_ws + WT4_BYTES);
        repack_w<<<dim3(SS * 8), dim3(256), 0, stream>>>(w, wt4);
        premod<<<dim3(BB * SS * 8), dim3(256), 0, stream>>>(wt4, kern, wmod);
        dwconv_big<<<dim3(640), dim3(256), 0, stream>>>(x, wmod, bias, out);
    } else if (ws_size >= WT4_BYTES + KERNF_BYTES) {
        unsigned short* wt4 = (unsigned short*)d_ws;
        float* kernf = (float*)((char*)d_ws + WT4_BYTES);
        repack_w<<<dim3(SS * 8), dim3(256), 0, stream>>>(w, wt4);
        repack_k<<<dim3(BB * KS), dim3(256), 0, stream>>>(kern, kernf);
        dwconv_mid<<<dim3(640), dim3(256), 0, stream>>>(x, wt4, kernf, bias, out);
    } else {
        const int total = BB * OO * PP;
        dwconv_naive<<<dim3((total + 255) / 256), dim3(256), 0, stream>>>(
            x, kern, w, bias, out);
    }
}